// Round 2
// baseline (103.379 us; speedup 1.0000x reference)
//
#include <hip/hip_runtime.h>

// CRF loss: A=8, S=200, B=64, T=32. scores (A,S,B,T,T) f32, targets (A,S,B) i32,
// mask (S,B) bool, a_mask (A,B) bool. Output: scalar f32 loss.
// Bool arrays may arrive as int32 (harness "integer -> int*" rule) or as uint8;
// detected at runtime from mask row 0 (always all-true).
constexpr int A_ = 8, S_ = 200, B_ = 64, T_ = 32;
constexpr int START_TAG = 30, END_TAG = 31;

__device__ __forceinline__ int load_flag(const void* p, bool u8, int idx) {
    return u8 ? (int)((const unsigned char*)p)[idx] : ((const int*)p)[idx];
}

// One wave (64 threads) per (a,b) chain. t = lane&31, f-half = lane>>5.
__global__ __launch_bounds__(64)
void crf_loss_kernel(const float* __restrict__ scores,
                     const int* __restrict__ targets,
                     const void* __restrict__ mask,
                     const void* __restrict__ amask,
                     float* __restrict__ out)
{
    const int chain = blockIdx.x;          // 0..511
    const int a = chain >> 6;              // chain / B_
    const int b = chain & (B_ - 1);
    const int lane = threadIdx.x;          // 0..63
    const int t = lane & 31;
    const int fbase = (lane >> 5) << 4;    // 0 or 16

    // ---- detect bool width: mask[0,0..3] all-true. int view: 1 -> int32, 0x01010101 -> uint8
    const bool bool_u8 = (((const int*)mask)[0] != 1);

    if (!load_flag(amask, bool_u8, a * B_ + b)) return;  // masked-out chain

    __shared__ int tg_lds[S_];
    __shared__ float part_lds[T_];

    // ---- first false mask index L (mask is a prefix mask: arange < length) ----
    int L = S_;
    for (int base = 0; base < S_; base += 64) {
        int i = base + lane;
        int mv = (i < S_) ? load_flag(mask, bool_u8, i * B_ + b) : 1;
        unsigned long long bal = __ballot(mv == 0);
        if (bal != 0ull && L == S_) L = base + (int)__builtin_ctzll(bal);
    }

    // ---- stage per-chain targets into LDS (used for fused gold-path gather) ----
    for (int i = lane; i < S_; i += 64)
        tg_lds[i] = targets[((size_t)a * S_ + i) * B_ + b];

    const size_t s_stride = (size_t)B_ * T_ * T_;                  // 65536 floats
    const float* cb = scores + ((size_t)a * S_ * B_ + b) * (T_ * T_);

    // ---- s = 0: partition0 = scores[a,0,b,START_TAG,:] ----
    float part = cb[START_TAG * T_ + t];   // lanes l and l+32 hold same t
    if (lane < 32) part_lds[lane] = part;

    float tg = 0.0f;                       // gold-path energy (same on all lanes)
    {
        int tg0 = tg_lds[0];
        float g = cb[tg0];                 // uniform address -> 1 transaction
        if (L > 0) tg = g;                 // mask[0] (always true in practice)
    }

    // Load one 32x32 tile for step SIDX into 16 regs (f = fbase..fbase+15, col t)
    // + the gold-path gather value (uniform address, line is resident anyway).
#define LOADT(BUF, GV, SIDX) do {                                        \
        const int sc_ = (SIDX);                                          \
        const float* p_ = cb + (size_t)sc_ * s_stride;                   \
        GV = p_[tg_lds[sc_]];                                            \
        _Pragma("unroll")                                                \
        for (int i_ = 0; i_ < 16; ++i_)                                  \
            BUF[i_] = p_[((fbase + i_) << 5) | t];                       \
    } while (0)

    // One scan step: part[t] = logsumexp_f(tile[f][t] + part[f]); tg += gather
#define STEPX(BUF, GV) do {                                              \
        float v_[16], mx_[16];                                           \
        _Pragma("unroll")                                                \
        for (int i_ = 0; i_ < 16; ++i_) {                                \
            v_[i_] = BUF[i_] + part_lds[fbase + i_];                     \
            mx_[i_] = v_[i_];                                            \
        }                                                                \
        _Pragma("unroll")                                                \
        for (int w_ = 8; w_ >= 1; w_ >>= 1)                              \
            for (int i_ = 0; i_ < w_; ++i_)                              \
                mx_[i_] = fmaxf(mx_[i_], mx_[i_ + w_]);                  \
        float vmax_ = mx_[0];                                            \
        _Pragma("unroll")                                                \
        for (int i_ = 0; i_ < 16; ++i_)                                  \
            v_[i_] = __expf(v_[i_] - vmax_);                             \
        _Pragma("unroll")                                                \
        for (int w_ = 8; w_ >= 1; w_ >>= 1)                              \
            for (int i_ = 0; i_ < w_; ++i_)                              \
                v_[i_] += v_[i_ + w_];                                   \
        float ssum_ = v_[0];                                             \
        float om_ = __shfl_xor(vmax_, 32);                               \
        float os_ = __shfl_xor(ssum_, 32);                               \
        float nm_ = fmaxf(vmax_, om_);                                   \
        float ns_ = ssum_ * __expf(vmax_ - nm_) + os_ * __expf(om_ - nm_); \
        part = nm_ + __logf(ns_);                                        \
        if (lane < 32) part_lds[lane] = part;                            \
        tg += GV;                                                        \
    } while (0)

    const int Sm1 = S_ - 1;
#define CLAMPS(x) ((x) < Sm1 ? (x) : Sm1)

    // ---- main scan s = 1..L-1, depth-3 register prefetch (4 rotating buffers) ----
    if (L > 1) {
        float b0[16], b1[16], b2[16], b3[16];
        float g0, g1, g2, g3;
        LOADT(b0, g0, CLAMPS(1));
        LOADT(b1, g1, CLAMPS(2));
        LOADT(b2, g2, CLAMPS(3));
        for (int s = 1; s < L; s += 4) {
            LOADT(b3, g3, CLAMPS(s + 3));
            STEPX(b0, g0);
            if (s + 1 >= L) break;
            LOADT(b0, g0, CLAMPS(s + 4));
            STEPX(b1, g1);
            if (s + 2 >= L) break;
            LOADT(b1, g1, CLAMPS(s + 5));
            STEPX(b2, g2);
            if (s + 3 >= L) break;
            LOADT(b2, g2, CLAMPS(s + 6));
            STEPX(b3, g3);
        }
    }

    // ---- epilogue: loss = logZ - tg_energy, accumulate ----
    float logZ = __shfl(part, END_TAG);    // partition[31]
    if (lane == 0)
        atomicAdd(out, (logZ - tg) * (1.0f / (float)B_));
}

extern "C" void kernel_launch(void* const* d_in, const int* in_sizes, int n_in,
                              void* d_out, int out_size, void* d_ws, size_t ws_size,
                              hipStream_t stream) {
    const float* scores = (const float*)d_in[0];
    const int* targets  = (const int*)d_in[1];
    const void* mask    = d_in[2];
    const void* amask   = d_in[3];
    float* out = (float*)d_out;

    hipMemsetAsync(out, 0, sizeof(float), stream);
    crf_loss_kernel<<<dim3(A_ * B_), dim3(64), 0, stream>>>(
        scores, targets, mask, amask, out);
}